// Round 4
// baseline (664.783 us; speedup 1.0000x reference)
//
#include <hip/hip_runtime.h>
#include <stdint.h>

// B=32, N=4096, D=256, S=8, H_MLP=512, 3 iterations.

typedef __attribute__((ext_vector_type(8))) short bf16x8;
typedef __attribute__((ext_vector_type(4))) float f32x4;

__device__ __forceinline__ float bf2f_lo(uint32_t u) {
    union { uint32_t u; float f; } v; v.u = u << 16; return v.f;
}
__device__ __forceinline__ float bf2f_hi(uint32_t u) {
    union { uint32_t u; float f; } v; v.u = u & 0xffff0000u; return v.f;
}
__device__ __forceinline__ unsigned short f2bf(float f) {
    union { float f; uint32_t u; } v; v.f = f;
    return (unsigned short)((v.u + 0x7fffu + ((v.u >> 16) & 1u)) >> 16);
}
__device__ __forceinline__ void unpack8(uint4 v, float* f) {
    f[0] = bf2f_lo(v.x); f[1] = bf2f_hi(v.x); f[2] = bf2f_lo(v.y); f[3] = bf2f_hi(v.y);
    f[4] = bf2f_lo(v.z); f[5] = bf2f_hi(v.z); f[6] = bf2f_lo(v.w); f[7] = bf2f_hi(v.w);
}
__device__ __forceinline__ float sigf(float x) { return 1.0f / (1.0f + __expf(-x)); }
__device__ __forceinline__ void gld_lds16(const void* g, void* l) {
    __builtin_amdgcn_global_load_lds(
        (__attribute__((address_space(1))) unsigned int*)g,
        (__attribute__((address_space(3))) unsigned int*)l, 16, 0, 0);
}

// ---------------------------------------------------------------------------
// Convert all weights to bf16, pack biases.
// ---------------------------------------------------------------------------
__global__ __launch_bounds__(256) void cvt_all(
    const float* __restrict__ Wk, const float* __restrict__ Wv,
    const float* __restrict__ W_ih, const float* __restrict__ W_hh,
    const float* __restrict__ W1, const float* __restrict__ W2,
    const float* __restrict__ Wq,
    const float* __restrict__ bk, const float* __restrict__ bv,
    const float* __restrict__ b_ih, const float* __restrict__ b_hh,
    unsigned short* __restrict__ Wkv, unsigned short* __restrict__ Wg,
    unsigned short* __restrict__ W1b, unsigned short* __restrict__ W2b,
    unsigned short* __restrict__ Wqb,
    float* __restrict__ bkv, float* __restrict__ bg) {
    int i = blockIdx.x * 256 + threadIdx.x;
    if (i < 131072)      Wkv[i] = f2bf(i < 65536 ? Wk[i] : Wv[i - 65536]);
    else if (i < 524288) { int j = i - 131072; Wg[j] = f2bf(j < 196608 ? W_ih[j] : W_hh[j - 196608]); }
    else if (i < 655360) W1b[i - 524288] = f2bf(W1[i - 524288]);
    else if (i < 786432) W2b[i - 655360] = f2bf(W2[i - 655360]);
    else                 Wqb[i - 786432] = f2bf(Wq[i - 786432]);
    if (i < 512)         bkv[i] = (i < 256 ? bk[i] : bv[i - 256]);
    else if (i < 2048)   { int j = i - 512; bg[j] = (j < 768 ? b_ih[j] : b_hh[j - 768]); }
}

// ---------------------------------------------------------------------------
// Fused LN(inputs) + K/V GEMM v2.  128-row tile x all 512 cols, 512 threads.
// As only (64 KB, XOR-swizzled); B fragments loaded directly from global
// (weights are 256 KB, L2-resident).  One barrier total.
// ---------------------------------------------------------------------------
__global__ __launch_bounds__(512, 2) void lngemm_kv(
    const float* __restrict__ in, const float* __restrict__ gg,
    const float* __restrict__ bb, const unsigned short* __restrict__ W,
    const float* __restrict__ bkv,
    unsigned short* __restrict__ Ko, unsigned short* __restrict__ Vo) {
    __shared__ __align__(16) unsigned short As[4 * 128 * 64];  // [slab][row][64] swizzled
    int t = threadIdx.x, wave = t >> 6, lane = t & 63;
    int m0 = blockIdx.x * 128;

    // ---- LN phase: 4 threads/row (q4 = t&3), fully coalesced reads ----
    {
        int row = t >> 2, q4 = t & 3;
        const float* rp = in + (size_t)(m0 + row) * 256;
        float s = 0.f, sq = 0.f;
        float4 xs[16];
#pragma unroll
        for (int slab = 0; slab < 4; ++slab)
#pragma unroll
            for (int h = 0; h < 4; ++h) {
                float4 x = *(const float4*)(rp + slab * 64 + h * 16 + q4 * 4);
                xs[slab * 4 + h] = x;
                s  += x.x + x.y + x.z + x.w;
                sq += x.x * x.x + x.y * x.y + x.z * x.z + x.w * x.w;
            }
        s  += __shfl_xor(s, 1, 64);  sq += __shfl_xor(sq, 1, 64);
        s  += __shfl_xor(s, 2, 64);  sq += __shfl_xor(sq, 2, 64);
        float mean = s * (1.0f / 256.0f);
        float rstd = rsqrtf(sq * (1.0f / 256.0f) - mean * mean + 1e-3f);
        int sw = row & 7;
#pragma unroll
        for (int slab = 0; slab < 4; ++slab)
#pragma unroll
            for (int h = 0; h < 4; ++h) {
                float4 x = xs[slab * 4 + h];
                int c = h * 16 + q4 * 4;                 // k within slab
                float4 g4 = *(const float4*)(gg + slab * 64 + c);
                float4 b4 = *(const float4*)(bb + slab * 64 + c);
                uint2 o;
                o.x = (uint32_t)f2bf((x.x - mean) * rstd * g4.x + b4.x) |
                      ((uint32_t)f2bf((x.y - mean) * rstd * g4.y + b4.y) << 16);
                o.y = (uint32_t)f2bf((x.z - mean) * rstd * g4.z + b4.z) |
                      ((uint32_t)f2bf((x.w - mean) * rstd * g4.w + b4.w) << 16);
                int chunk = (c >> 3) ^ sw;
                *(uint2*)&As[(slab * 128 + row) * 64 + chunk * 8 + (c & 7)] = o;
            }
    }
    __syncthreads();

    int wr = wave >> 2, wc = wave & 3;  // 2 x 4 wave grid, 64x128 each
    f32x4 acc[4][8];
#pragma unroll
    for (int i = 0; i < 4; ++i)
#pragma unroll
        for (int j = 0; j < 8; ++j)
#pragma unroll
            for (int r = 0; r < 4; ++r) acc[i][j][r] = 0.f;

#pragma unroll
    for (int kb = 0; kb < 4; ++kb) {
#pragma unroll
        for (int kk2 = 0; kk2 < 2; ++kk2) {
            int koff = kk2 * 32 + (lane >> 4) * 8;   // k elem within slab
            bf16x8 af[4], bf[8];
#pragma unroll
            for (int ti = 0; ti < 4; ++ti) {
                int r = wr * 64 + ti * 16 + (lane & 15);
                af[ti] = *(const bf16x8*)&As[(kb * 128 + r) * 64 +
                                             (((koff >> 3) ^ (r & 7)) << 3)];
            }
#pragma unroll
            for (int tj = 0; tj < 8; ++tj) {
                int col = wc * 128 + tj * 16 + (lane & 15);
                bf[tj] = *(const bf16x8*)(W + (size_t)col * 256 + kb * 64 + koff);
            }
#pragma unroll
            for (int ti = 0; ti < 4; ++ti)
#pragma unroll
                for (int tj = 0; tj < 8; ++tj)
                    acc[ti][tj] = __builtin_amdgcn_mfma_f32_16x16x32_bf16(
                        af[ti], bf[tj], acc[ti][tj], 0, 0, 0);
        }
    }
#pragma unroll
    for (int ti = 0; ti < 4; ++ti)
#pragma unroll
        for (int tj = 0; tj < 8; ++tj) {
            int col = wc * 128 + tj * 16 + (lane & 15);
            float bias = bkv[col];
            unsigned short* base = (col < 256) ? Ko : Vo;
            int outc = col & 255;
#pragma unroll
            for (int r = 0; r < 4; ++r) {
                int row = m0 + wr * 64 + ti * 16 + (lane >> 4) * 4 + r;
                base[(size_t)row * 256 + outc] = f2bf(acc[ti][tj][r] + bias);
            }
        }
}

// ---------------------------------------------------------------------------
// MFMA GEMM with row-LayerNorm fused into A staging; q0 = LN(slots)@Wq^T+bq.
// (initial q only; later iterations produce q inside slot_tail)
// ---------------------------------------------------------------------------
__global__ __launch_bounds__(256) void mfma_gemm_ln(
    const float* __restrict__ src, const float* __restrict__ lng,
    const float* __restrict__ lnb, const unsigned short* __restrict__ Bw,
    const float* __restrict__ bias, unsigned short* __restrict__ outb) {
    constexpr int ALD = 264;
    __shared__ __align__(16) unsigned short As[128 * ALD];
    __shared__ __align__(16) unsigned short Bs[128 * 64];
    int t = threadIdx.x, wave = t >> 6, lane = t & 63;
    int wr = wave >> 1, wc = wave & 1;
    int m0 = blockIdx.x * 128, j0 = blockIdx.y * 128;

    float4 g4 = *(const float4*)(lng + lane * 4);
    float4 b4 = *(const float4*)(lnb + lane * 4);
    for (int r = 0; r < 32; ++r) {
        int row = wave * 32 + r;
        float4 x = *(const float4*)(src + (size_t)(m0 + row) * 256 + lane * 4);
        float s  = x.x + x.y + x.z + x.w;
        float sq = x.x * x.x + x.y * x.y + x.z * x.z + x.w * x.w;
#pragma unroll
        for (int off = 32; off > 0; off >>= 1) {
            s  += __shfl_xor(s,  off, 64);
            sq += __shfl_xor(sq, off, 64);
        }
        float mean = s * (1.0f / 256.0f);
        float rstd = rsqrtf(sq * (1.0f / 256.0f) - mean * mean + 1e-3f);
        uint2 o;
        o.x = (uint32_t)f2bf((x.x - mean) * rstd * g4.x + b4.x) |
              ((uint32_t)f2bf((x.y - mean) * rstd * g4.y + b4.y) << 16);
        o.y = (uint32_t)f2bf((x.z - mean) * rstd * g4.z + b4.z) |
              ((uint32_t)f2bf((x.w - mean) * rstd * g4.w + b4.w) << 16);
        *(uint2*)&As[row * ALD + lane * 4] = o;
    }
    __syncthreads();

    f32x4 acc[4][4];
#pragma unroll
    for (int i = 0; i < 4; ++i)
#pragma unroll
        for (int j = 0; j < 4; ++j)
#pragma unroll
            for (int r = 0; r < 4; ++r) acc[i][j][r] = 0.f;

    for (int kb = 0; kb < 4; ++kb) {
        int k0 = kb * 64;
#pragma unroll
        for (int i = 0; i < 4; ++i) {
            int rbase = wave * 32 + i * 8;
            gld_lds16(Bw + (size_t)(j0 + rbase + (lane >> 3)) * 256 + k0 + (lane & 7) * 8,
                      &Bs[rbase * 64]);
        }
        __syncthreads();
#pragma unroll
        for (int kk = 0; kk < 64; kk += 32) {
            int koff = kk + (lane >> 4) * 8;
            bf16x8 af[4], bf[4];
#pragma unroll
            for (int ti = 0; ti < 4; ++ti)
                af[ti] = *(const bf16x8*)&As[(wr * 64 + ti * 16 + (lane & 15)) * ALD + k0 + koff];
#pragma unroll
            for (int tj = 0; tj < 4; ++tj)
                bf[tj] = *(const bf16x8*)&Bs[(wc * 64 + tj * 16 + (lane & 15)) * 64 + koff];
#pragma unroll
            for (int ti = 0; ti < 4; ++ti)
#pragma unroll
                for (int tj = 0; tj < 4; ++tj)
                    acc[ti][tj] = __builtin_amdgcn_mfma_f32_16x16x32_bf16(
                        af[ti], bf[tj], acc[ti][tj], 0, 0, 0);
        }
        __syncthreads();
    }
#pragma unroll
    for (int ti = 0; ti < 4; ++ti)
#pragma unroll
        for (int tj = 0; tj < 4; ++tj) {
            int col = j0 + wc * 64 + tj * 16 + (lane & 15);
            float bs = bias[col];
#pragma unroll
            for (int r = 0; r < 4; ++r) {
                int row = m0 + wr * 64 + ti * 16 + (lane >> 4) * 4 + r;
                outb[(size_t)row * 256 + col] = f2bf(acc[ti][tj][r] + bs);
            }
        }
}

// ---------------------------------------------------------------------------
// Fused attention v2: chunk = 256 n, grid (32,16) = 512 blocks (2/CU).
// Deterministic partial outputs (no atomics, no memset needed).
// ---------------------------------------------------------------------------
__global__ __launch_bounds__(256) void attn_fused(
    const unsigned short* __restrict__ qb, const unsigned short* __restrict__ K,
    const unsigned short* __restrict__ V,
    float* __restrict__ upd_p,               // [16][32*2048]
    float* __restrict__ sums_p) {            // [16][256]
    __shared__ __align__(16) unsigned short qs[8 * 256];
    __shared__ __align__(16) float atf[8 * 256];
    __shared__ __align__(16) float pr[4][8 * 256];
    __shared__ float ssum[8];
    int b = blockIdx.x, ch = blockIdx.y, t = threadIdx.x;
    int wave = t >> 6, lane = t & 63;

    *(uint4*)&qs[t * 8] = ((const uint4*)(qb + b * 2048))[t];
    if (t < 8) ssum[t] = 0.f;
    __syncthreads();

    // ---- dots: thread tile 4 slots x 2 n ----
    int sg = t >> 7, np = t & 127;
    int nbase = ch * 256 + np * 2;
    const unsigned short* kr = K + ((size_t)b * 4096 + nbase) * 256;
    float acc[4][2];
#pragma unroll
    for (int i = 0; i < 4; ++i) { acc[i][0] = 0.f; acc[i][1] = 0.f; }
    for (int c = 0; c < 32; ++c) {
        float qf[4][8];
#pragma unroll
        for (int si = 0; si < 4; ++si)
            unpack8(*(const uint4*)&qs[(sg * 4 + si) * 256 + c * 8], qf[si]);
#pragma unroll
        for (int r = 0; r < 2; ++r) {
            float kf[8];
            unpack8(*(const uint4*)(kr + (size_t)r * 256 + c * 8), kf);
#pragma unroll
            for (int si = 0; si < 4; ++si)
                acc[si][r] += qf[si][0] * kf[0] + qf[si][1] * kf[1] +
                              qf[si][2] * kf[2] + qf[si][3] * kf[3] +
                              qf[si][4] * kf[4] + qf[si][5] * kf[5] +
                              qf[si][6] * kf[6] + qf[si][7] * kf[7];
        }
    }
#pragma unroll
    for (int si = 0; si < 4; ++si) {
        atf[(sg * 4 + si) * 256 + np * 2 + 0] = acc[si][0] * 0.0625f;
        atf[(sg * 4 + si) * 256 + np * 2 + 1] = acc[si][1] * 0.0625f;
    }
    __syncthreads();

    // ---- softmax over slots, 1 n per thread ----
    {
        int n = t;
        float v[8];
#pragma unroll
        for (int s = 0; s < 8; ++s) v[s] = atf[s * 256 + n];
        float m = v[0];
#pragma unroll
        for (int s = 1; s < 8; ++s) m = fmaxf(m, v[s]);
        float sum = 0.f;
#pragma unroll
        for (int s = 0; s < 8; ++s) { v[s] = __expf(v[s] - m); sum += v[s]; }
        float inv = 1.0f / sum;
        float ts[8];
#pragma unroll
        for (int s = 0; s < 8; ++s) {
            float a = v[s] * inv + 1e-8f;
            atf[s * 256 + n] = a;
            ts[s] = a;
        }
#pragma unroll
        for (int s = 0; s < 8; ++s) {
#pragma unroll
            for (int off = 32; off > 0; off >>= 1)
                ts[s] += __shfl_xor(ts[s], off, 64);
        }
        if (lane == 0) {
#pragma unroll
            for (int s = 0; s < 8; ++s) atomicAdd(&ssum[s], ts[s]);
        }
    }
    __syncthreads();
    if (t < 8) sums_p[ch * 256 + b * 8 + t] = ssum[t];

    // ---- update: wave covers 64 n, lane owns d-quad ----
    float ua[8][4];
#pragma unroll
    for (int s = 0; s < 8; ++s)
#pragma unroll
        for (int k = 0; k < 4; ++k) ua[s][k] = 0.f;
    const unsigned short* vb = V + ((size_t)b * 4096 + ch * 256 + wave * 64) * 256 + lane * 4;
    for (int g = 0; g < 16; ++g) {
        int nl = wave * 64 + g * 4;
        float4 a4[8];
#pragma unroll
        for (int s = 0; s < 8; ++s) a4[s] = *(const float4*)&atf[s * 256 + nl];
        const unsigned short* vrow = vb + (size_t)g * 4 * 256;
#define UPD_STEP(kk, comp)                                                     \
        {                                                                      \
            uint2 vv = *(const uint2*)(vrow + (size_t)kk * 256);               \
            float v0 = bf2f_lo(vv.x), v1 = bf2f_hi(vv.x);                      \
            float v2 = bf2f_lo(vv.y), v3 = bf2f_hi(vv.y);                      \
            _Pragma("unroll")                                                  \
            for (int s = 0; s < 8; ++s) {                                      \
                float a = a4[s].comp;                                          \
                ua[s][0] += a * v0; ua[s][1] += a * v1;                        \
                ua[s][2] += a * v2; ua[s][3] += a * v3;                        \
            }                                                                  \
        }
        UPD_STEP(0, x) UPD_STEP(1, y) UPD_STEP(2, z) UPD_STEP(3, w)
#undef UPD_STEP
    }
#pragma unroll
    for (int s = 0; s < 8; ++s)
        *(float4*)&pr[wave][s * 256 + lane * 4] = *(float4*)ua[s];
    __syncthreads();
    for (int i = t; i < 2048; i += 256)
        upd_p[(size_t)ch * 65536 + (size_t)b * 2048 + i] =
            pr[0][i] + pr[1][i] + pr[2][i] + pr[3][i];
}

// ---------------------------------------------------------------------------
// Slot tail v2: reduce attn partials + gates GEMM + GRU + LN + MLP1 + MLP2 +
// residual (+ slot-LN + q GEMM unless last iter).  One block per batch.
// All weight fragments loaded directly from global (L2-hot).
// ---------------------------------------------------------------------------
__global__ __launch_bounds__(256) void slot_tail(
    const float* __restrict__ upd_p, const float* __restrict__ sums_p,
    const float* __restrict__ cur,
    const unsigned short* __restrict__ Wg, const float* __restrict__ bg,
    const float* __restrict__ g_mlp, const float* __restrict__ b_mlp,
    const unsigned short* __restrict__ W1b, const float* __restrict__ b1,
    const unsigned short* __restrict__ W2b, const float* __restrict__ b2,
    const float* __restrict__ g_slot, const float* __restrict__ b_slot,
    const unsigned short* __restrict__ Wqb, const float* __restrict__ bq,
    float* __restrict__ slots_out, unsigned short* __restrict__ qbuf,
    int do_q) {
    __shared__ float gts[8 * 1536];                    // 48 KB
    __shared__ float hn[2048];
    __shared__ float sn[2048];
    __shared__ __align__(16) unsigned short A1u[8 * 264];
    __shared__ __align__(16) unsigned short A1h[8 * 264];
    __shared__ __align__(16) unsigned short A1[8 * 264];
    __shared__ __align__(16) unsigned short A2[8 * 520];
    __shared__ float ssum8[8];
    int b = blockIdx.x, t = threadIdx.x;
    int wave = t >> 6, lane = t & 63;

    // ---- stage u (reduced, normalized) and h as bf16 A-operands ----
    if (t < 8) {
        float s = 0.f;
#pragma unroll
        for (int c = 0; c < 16; ++c) s += sums_p[c * 256 + b * 8 + t];
        ssum8[t] = s;
    }
    __syncthreads();
    for (int idx = t; idx < 2048; idx += 256) {
        int row = idx >> 8, d = idx & 255;
        float us = 0.f;
#pragma unroll
        for (int c = 0; c < 16; ++c) us += upd_p[(size_t)c * 65536 + b * 2048 + idx];
        A1u[row * 264 + d] = f2bf(us / ssum8[row]);
        A1h[row * 264 + d] = f2bf(cur[(size_t)b * 2048 + idx]);
    }
    __syncthreads();

    // ---- gates GEMM: [8 x 1536], cols 0-767 u@W_ih, 768-1535 h@W_hh ----
    {
        const unsigned short* Af = (wave < 2) ? A1u : A1h;
        bf16x8 af[8];
#pragma unroll
        for (int ks = 0; ks < 8; ++ks)
            af[ks] = *(const bf16x8*)&Af[(lane & 15) * 264 + ks * 32 + (lane >> 4) * 8];
#pragma unroll
        for (int nt = 0; nt < 24; ++nt) {
            int n0 = wave * 384 + nt * 16;
            f32x4 a = {0.f, 0.f, 0.f, 0.f};
#pragma unroll
            for (int ks = 0; ks < 8; ++ks) {
                bf16x8 bfr = *(const bf16x8*)(Wg + (size_t)(n0 + (lane & 15)) * 256 +
                                              ks * 32 + (lane >> 4) * 8);
                a = __builtin_amdgcn_mfma_f32_16x16x32_bf16(af[ks], bfr, a, 0, 0, 0);
            }
            int col = n0 + (lane & 15);
            float bs = bg[col];
#pragma unroll
            for (int r = 0; r < 4; ++r) {
                int row = (lane >> 4) * 4 + r;
                if (row < 8) gts[row * 1536 + col] = a[r] + bs;
            }
        }
    }
    __syncthreads();

    // ---- GRU combine ----
#pragma unroll
    for (int p = 0; p < 8; ++p) {
        int idx = p * 256 + t;
        int s = idx >> 8, j = idx & 255;
        const float* gr = &gts[s * 1536];
        float r  = sigf(gr[j] + gr[768 + j]);
        float z  = sigf(gr[256 + j] + gr[1024 + j]);
        float nn = tanhf(gr[512 + j] + r * gr[1280 + j]);
        float h  = cur[(size_t)b * 2048 + idx];
        hn[idx] = (1.0f - z) * nn + z * h;
    }
    __syncthreads();

    // ---- LN(mlp) -> A1 ----
    {
        float4 g4 = *(const float4*)(g_mlp + lane * 4);
        float4 b4 = *(const float4*)(b_mlp + lane * 4);
#pragma unroll
        for (int rep = 0; rep < 2; ++rep) {
            int s = wave * 2 + rep;
            float4 x = *(const float4*)&hn[s * 256 + lane * 4];
            float sm = x.x + x.y + x.z + x.w;
            float sq = x.x * x.x + x.y * x.y + x.z * x.z + x.w * x.w;
#pragma unroll
            for (int off = 32; off > 0; off >>= 1) {
                sm += __shfl_xor(sm, off, 64);
                sq += __shfl_xor(sq, off, 64);
            }
            float mean = sm * (1.0f / 256.0f);
            float rstd = rsqrtf(sq * (1.0f / 256.0f) - mean * mean + 1e-3f);
            uint2 o;
            o.x = (uint32_t)f2bf((x.x - mean) * rstd * g4.x + b4.x) |
                  ((uint32_t)f2bf((x.y - mean) * rstd * g4.y + b4.y) << 16);
            o.y = (uint32_t)f2bf((x.z - mean) * rstd * g4.z + b4.z) |
                  ((uint32_t)f2bf((x.w - mean) * rstd * g4.w + b4.w) << 16);
            *(uint2*)&A1[s * 264 + lane * 4] = o;
        }
    }
    __syncthreads();

    // ---- MLP1: A2 = relu(A1 @ W1^T + b1) ----
    {
        bf16x8 af[8];
#pragma unroll
        for (int ks = 0; ks < 8; ++ks)
            af[ks] = *(const bf16x8*)&A1[(lane & 15) * 264 + ks * 32 + (lane >> 4) * 8];
#pragma unroll
        for (int nt = 0; nt < 8; ++nt) {
            int n0 = (wave * 8 + nt) * 16;
            f32x4 a = {0.f, 0.f, 0.f, 0.f};
#pragma unroll
            for (int ks = 0; ks < 8; ++ks) {
                bf16x8 bfr = *(const bf16x8*)(W1b + (size_t)(n0 + (lane & 15)) * 256 +
                                              ks * 32 + (lane >> 4) * 8);
                a = __builtin_amdgcn_mfma_f32_16x16x32_bf16(af[ks], bfr, a, 0, 0, 0);
            }
            int col = n0 + (lane & 15);
            float bs = b1[col];
#pragma unroll
            for (int r = 0; r < 4; ++r) {
                int row = (lane >> 4) * 4 + r;
                if (row < 8) A2[row * 520 + col] = f2bf(fmaxf(a[r] + bs, 0.f));
            }
        }
    }
    __syncthreads();

    // ---- MLP2: sn = A2 @ W2^T + b2 + hn; write new slots ----
    {
        bf16x8 af[16];
#pragma unroll
        for (int ks = 0; ks < 16; ++ks)
            af[ks] = *(const bf16x8*)&A2[(lane & 15) * 520 + ks * 32 + (lane >> 4) * 8];
#pragma unroll
        for (int nt = 0; nt < 4; ++nt) {
            int n0 = (wave * 4 + nt) * 16;
            f32x4 a = {0.f, 0.f, 0.f, 0.f};
#pragma unroll
            for (int ks = 0; ks < 16; ++ks) {
                bf16x8 bfr = *(const bf16x8*)(W2b + (size_t)(n0 + (lane & 15)) * 512 +
                                              ks * 32 + (lane >> 4) * 8);
                a = __builtin_amdgcn_mfma_f32_16x16x32_bf16(af[ks], bfr, a, 0, 0, 0);
            }
            int col = n0 + (lane & 15);
            float bs = b2[col];
#pragma unroll
            for (int r = 0; r < 4; ++r) {
                int row = (lane >> 4) * 4 + r;
                if (row < 8) {
                    float v = a[r] + bs + hn[row * 256 + col];
                    sn[row * 256 + col] = v;
                    slots_out[((size_t)b * 8 + row) * 256 + col] = v;
                }
            }
        }
    }
    if (!do_q) return;
    __syncthreads();

    // ---- LN(slot) on sn -> A1 ----
    {
        float4 g4 = *(const float4*)(g_slot + lane * 4);
        float4 b4 = *(const float4*)(b_slot + lane * 4);
#pragma unroll
        for (int rep = 0; rep < 2; ++rep) {
            int s = wave * 2 + rep;
            float4 x = *(const float4*)&sn[s * 256 + lane * 4];
            float sm = x.x + x.y + x.z + x.w;
            float sq = x.x * x.x + x.y * x.y + x.z * x.z + x.w * x.w;
#pragma unroll
            for (int off = 32; off > 0; off >>= 1) {
                sm += __shfl_xor(sm, off, 64);
                sq += __shfl_xor(sq, off, 64);
            }
            float mean = sm * (1.0f / 256.0f);
            float rstd = rsqrtf(sq * (1.0f / 256.0f) - mean * mean + 1e-3f);
            uint2 o;
            o.x = (uint32_t)f2bf((x.x - mean) * rstd * g4.x + b4.x) |
                  ((uint32_t)f2bf((x.y - mean) * rstd * g4.y + b4.y) << 16);
            o.y = (uint32_t)f2bf((x.z - mean) * rstd * g4.z + b4.z) |
                  ((uint32_t)f2bf((x.w - mean) * rstd * g4.w + b4.w) << 16);
            *(uint2*)&A1[s * 264 + lane * 4] = o;
        }
    }
    __syncthreads();

    // ---- q = A1 @ Wq^T + bq -> qbuf bf16 ----
    {
        bf16x8 af[8];
#pragma unroll
        for (int ks = 0; ks < 8; ++ks)
            af[ks] = *(const bf16x8*)&A1[(lane & 15) * 264 + ks * 32 + (lane >> 4) * 8];
#pragma unroll
        for (int nt = 0; nt < 4; ++nt) {
            int n0 = (wave * 4 + nt) * 16;
            f32x4 a = {0.f, 0.f, 0.f, 0.f};
#pragma unroll
            for (int ks = 0; ks < 8; ++ks) {
                bf16x8 bfr = *(const bf16x8*)(Wqb + (size_t)(n0 + (lane & 15)) * 256 +
                                              ks * 32 + (lane >> 4) * 8);
                a = __builtin_amdgcn_mfma_f32_16x16x32_bf16(af[ks], bfr, a, 0, 0, 0);
            }
            int col = n0 + (lane & 15);
            float bs = bq[col];
#pragma unroll
            for (int r = 0; r < 4; ++r) {
                int row = (lane >> 4) * 4 + r;
                if (row < 8)
                    qbuf[((size_t)b * 8 + row) * 256 + col] = f2bf(a[r] + bs);
            }
        }
    }
}

// ---------------------------------------------------------------------------
extern "C" void kernel_launch(void* const* d_in, const int* in_sizes, int n_in,
                              void* d_out, int out_size, void* d_ws, size_t ws_size,
                              hipStream_t stream) {
    const float* inputs    = (const float*)d_in[0];
    const float* slots_in  = (const float*)d_in[1];
    const float* ln_in_g   = (const float*)d_in[3];
    const float* ln_in_b   = (const float*)d_in[4];
    const float* ln_slot_g = (const float*)d_in[5];
    const float* ln_slot_b = (const float*)d_in[6];
    const float* ln_mlp_g  = (const float*)d_in[7];
    const float* ln_mlp_b  = (const float*)d_in[8];
    const float* Wq   = (const float*)d_in[9];
    const float* bq   = (const float*)d_in[10];
    const float* Wk   = (const float*)d_in[11];
    const float* bk   = (const float*)d_in[12];
    const float* Wv   = (const float*)d_in[13];
    const float* bv   = (const float*)d_in[14];
    const float* W_ih = (const float*)d_in[15];
    const float* b_ih = (const float*)d_in[16];
    const float* W_hh = (const float*)d_in[17];
    const float* b_hh = (const float*)d_in[18];
    const float* W1   = (const float*)d_in[19];
    const float* b1   = (const float*)d_in[20];
    const float* W2   = (const float*)d_in[21];
    const float* b2   = (const float*)d_in[22];

    char* p = (char*)d_ws;
    size_t off = 0;
    auto take = [&](size_t bytes) -> char* {
        char* r = p + off;
        off += (bytes + 255) & ~(size_t)255;
        return r;
    };
    unsigned short* Kb   = (unsigned short*)take((size_t)131072 * 256 * 2);
    unsigned short* Vb   = (unsigned short*)take((size_t)131072 * 256 * 2);
    unsigned short* Wkv  = (unsigned short*)take(131072 * 2);
    unsigned short* Wg   = (unsigned short*)take(393216 * 2);
    unsigned short* W1b  = (unsigned short*)take(131072 * 2);
    unsigned short* W2b  = (unsigned short*)take(131072 * 2);
    unsigned short* Wqb  = (unsigned short*)take(65536 * 2);
    float* bkv   = (float*)take(512 * 4);
    float* bg    = (float*)take(1536 * 4);
    unsigned short* qbuf = (unsigned short*)take(65536 * 2);
    float* upd_p = (float*)take((size_t)16 * 65536 * 4);
    float* sums_p= (float*)take(16 * 256 * 4);
    float* sA    = (float*)take(65536 * 4);
    float* sB    = (float*)take(65536 * 4);

    cvt_all<<<3328, 256, 0, stream>>>(Wk, Wv, W_ih, W_hh, W1, W2, Wq,
                                      bk, bv, b_ih, b_hh,
                                      Wkv, Wg, W1b, W2b, Wqb, bkv, bg);
    lngemm_kv<<<1024, 512, 0, stream>>>(inputs, ln_in_g, ln_in_b, Wkv, bkv, Kb, Vb);
    mfma_gemm_ln<<<dim3(2, 2), 256, 0, stream>>>(slots_in, ln_slot_g, ln_slot_b,
                                                 Wqb, bq, qbuf);

    const float* cur = slots_in;
    float* nxt[3] = {sA, sB, (float*)d_out};
    for (int it = 0; it < 3; ++it) {
        attn_fused<<<dim3(32, 16), 256, 0, stream>>>(qbuf, Kb, Vb, upd_p, sums_p);
        slot_tail<<<32, 256, 0, stream>>>(upd_p, sums_p, cur, Wg, bg,
                                          ln_mlp_g, ln_mlp_b, W1b, b1, W2b, b2,
                                          ln_slot_g, ln_slot_b, Wqb, bq,
                                          nxt[it], qbuf, it < 2 ? 1 : 0);
        cur = nxt[it];
    }
    (void)in_sizes; (void)n_in; (void)out_size; (void)ws_size;
}

// Round 5
// 618.178 us; speedup vs baseline: 1.0754x; 1.0754x over previous
//
#include <hip/hip_runtime.h>
#include <stdint.h>

// B=32, N=4096, D=256, S=8, H_MLP=512, 3 iterations.

typedef __attribute__((ext_vector_type(8))) short bf16x8;
typedef __attribute__((ext_vector_type(4))) float f32x4;

__device__ __forceinline__ float bf2f_lo(uint32_t u) {
    union { uint32_t u; float f; } v; v.u = u << 16; return v.f;
}
__device__ __forceinline__ float bf2f_hi(uint32_t u) {
    union { uint32_t u; float f; } v; v.u = u & 0xffff0000u; return v.f;
}
__device__ __forceinline__ unsigned short f2bf(float f) {
    union { float f; uint32_t u; } v; v.f = f;
    return (unsigned short)((v.u + 0x7fffu + ((v.u >> 16) & 1u)) >> 16);
}
__device__ __forceinline__ void unpack8(uint4 v, float* f) {
    f[0] = bf2f_lo(v.x); f[1] = bf2f_hi(v.x); f[2] = bf2f_lo(v.y); f[3] = bf2f_hi(v.y);
    f[4] = bf2f_lo(v.z); f[5] = bf2f_hi(v.z); f[6] = bf2f_lo(v.w); f[7] = bf2f_hi(v.w);
}
__device__ __forceinline__ float sigf(float x) { return 1.0f / (1.0f + __expf(-x)); }
__device__ __forceinline__ void gld_lds16(const void* g, void* l) {
    __builtin_amdgcn_global_load_lds(
        (__attribute__((address_space(1))) unsigned int*)g,
        (__attribute__((address_space(3))) unsigned int*)l, 16, 0, 0);
}

// ---------------------------------------------------------------------------
// prep_k: three grid segments in one dispatch.
//   [0, 32768)        LN(inputs) -> xbf (bf16, chunk-XOR-swizzled layout)
//   [32768, 36096)    weight cvt fp32->bf16 (Wkv swizzled; others linear)
//   [36096, 36128)    q0 = LN_slot(slots_in) @ Wq^T + bq  (fp32 Wq direct)
// ---------------------------------------------------------------------------
__global__ __launch_bounds__(256) void prep_k(
    const float* __restrict__ in, const float* __restrict__ ln_in_g,
    const float* __restrict__ ln_in_b, unsigned short* __restrict__ xbf,
    const float* __restrict__ Wk, const float* __restrict__ Wv,
    const float* __restrict__ W_ih, const float* __restrict__ W_hh,
    const float* __restrict__ W1, const float* __restrict__ W2,
    const float* __restrict__ bk, const float* __restrict__ bv,
    const float* __restrict__ b_ih, const float* __restrict__ b_hh,
    unsigned short* __restrict__ Wkv, unsigned short* __restrict__ Wg,
    unsigned short* __restrict__ W1b, unsigned short* __restrict__ W2b,
    float* __restrict__ bkv, float* __restrict__ bg,
    const float* __restrict__ slots_in, const float* __restrict__ g_slot,
    const float* __restrict__ b_slot, const float* __restrict__ Wq,
    const float* __restrict__ bq, unsigned short* __restrict__ qbuf) {
    __shared__ __align__(16) unsigned short A1[8 * 264];
    int bid = blockIdx.x, t = threadIdx.x;
    int wave = t >> 6, lane = t & 63;

    if (bid < 32768) {
        // ---- LayerNorm inputs, one row per wave, swizzled bf16 out ----
        size_t row = (size_t)bid * 4 + wave;
        const float4 x = *(const float4*)(in + row * 256 + lane * 4);
        float s  = x.x + x.y + x.z + x.w;
        float sq = x.x * x.x + x.y * x.y + x.z * x.z + x.w * x.w;
#pragma unroll
        for (int off = 32; off > 0; off >>= 1) {
            s  += __shfl_xor(s,  off, 64);
            sq += __shfl_xor(sq, off, 64);
        }
        float mean = s * (1.0f / 256.0f);
        float rstd = rsqrtf(sq * (1.0f / 256.0f) - mean * mean + 1e-3f);
        float4 g4 = *(const float4*)(ln_in_g + lane * 4);
        float4 b4 = *(const float4*)(ln_in_b + lane * 4);
        uint2 o;
        o.x = (uint32_t)f2bf((x.x - mean) * rstd * g4.x + b4.x) |
              ((uint32_t)f2bf((x.y - mean) * rstd * g4.y + b4.y) << 16);
        o.y = (uint32_t)f2bf((x.z - mean) * rstd * g4.z + b4.z) |
              ((uint32_t)f2bf((x.w - mean) * rstd * g4.w + b4.w) << 16);
        int dst = (((lane >> 1) ^ ((int)row & 7)) << 3) + (lane & 1) * 4;
        *(uint2*)(xbf + row * 256 + dst) = o;
        return;
    }
    if (bid < 36096) {
        int i = (bid - 32768) * 256 + t;
        if (i < 131072) {
            float v = (i < 65536) ? Wk[i] : Wv[i - 65536];
            int col = i >> 8, k = i & 255;
            int dk = ((((k >> 3) ^ (col & 7)) << 3) | (k & 7));
            Wkv[col * 256 + dk] = f2bf(v);
        } else if (i < 524288) {
            int j = i - 131072;
            Wg[j] = f2bf(j < 196608 ? W_ih[j] : W_hh[j - 196608]);
        } else if (i < 655360) W1b[i - 524288] = f2bf(W1[i - 524288]);
        else                   W2b[i - 655360] = f2bf(W2[i - 655360]);
        if (i < 512)           bkv[i] = (i < 256 ? bk[i] : bv[i - 256]);
        else if (i < 2048)   { int j = i - 512; bg[j] = (j < 768 ? b_ih[j] : b_hh[j - 768]); }
        return;
    }
    // ---- q0 segment: one block per batch ----
    int b = bid - 36096;
    {
        float4 g4 = *(const float4*)(g_slot + lane * 4);
        float4 b4 = *(const float4*)(b_slot + lane * 4);
#pragma unroll
        for (int rep = 0; rep < 2; ++rep) {
            int s = wave * 2 + rep;
            float4 x = *(const float4*)(slots_in + (size_t)b * 2048 + s * 256 + lane * 4);
            float sm = x.x + x.y + x.z + x.w;
            float sq = x.x * x.x + x.y * x.y + x.z * x.z + x.w * x.w;
#pragma unroll
            for (int off = 32; off > 0; off >>= 1) {
                sm += __shfl_xor(sm, off, 64);
                sq += __shfl_xor(sq, off, 64);
            }
            float mean = sm * (1.0f / 256.0f);
            float rstd = rsqrtf(sq * (1.0f / 256.0f) - mean * mean + 1e-3f);
            uint2 o;
            o.x = (uint32_t)f2bf((x.x - mean) * rstd * g4.x + b4.x) |
                  ((uint32_t)f2bf((x.y - mean) * rstd * g4.y + b4.y) << 16);
            o.y = (uint32_t)f2bf((x.z - mean) * rstd * g4.z + b4.z) |
                  ((uint32_t)f2bf((x.w - mean) * rstd * g4.w + b4.w) << 16);
            *(uint2*)&A1[s * 264 + lane * 4] = o;
        }
    }
    __syncthreads();
    {
        bf16x8 af[8];
#pragma unroll
        for (int ks = 0; ks < 8; ++ks)
            af[ks] = *(const bf16x8*)&A1[(lane & 15) * 264 + ks * 32 + (lane >> 4) * 8];
#pragma unroll
        for (int nt = 0; nt < 4; ++nt) {
            int n0 = (wave * 4 + nt) * 16;
            f32x4 a = {0.f, 0.f, 0.f, 0.f};
#pragma unroll
            for (int ks = 0; ks < 8; ++ks) {
                const float* wp = Wq + (size_t)(n0 + (lane & 15)) * 256 +
                                  ks * 32 + (lane >> 4) * 8;
                float4 wa = *(const float4*)wp;
                float4 wb = *(const float4*)(wp + 4);
                bf16x8 bfr;
                bfr[0] = (short)f2bf(wa.x); bfr[1] = (short)f2bf(wa.y);
                bfr[2] = (short)f2bf(wa.z); bfr[3] = (short)f2bf(wa.w);
                bfr[4] = (short)f2bf(wb.x); bfr[5] = (short)f2bf(wb.y);
                bfr[6] = (short)f2bf(wb.z); bfr[7] = (short)f2bf(wb.w);
                a = __builtin_amdgcn_mfma_f32_16x16x32_bf16(af[ks], bfr, a, 0, 0, 0);
            }
            int col = n0 + (lane & 15);
            float bs = bq[col];
#pragma unroll
            for (int r = 0; r < 4; ++r) {
                int row = (lane >> 4) * 4 + r;
                if (row < 8)
                    qbuf[((size_t)b * 8 + row) * 256 + col] = f2bf(a[r] + bs);
            }
        }
    }
}

// ---------------------------------------------------------------------------
// K/V GEMM (round-2 structure + XCD swizzle + conflict-free swizzled LDS).
// C[131072,512] = X@Wkv^T -> K,V bf16.  128x128 tiles, global_load_lds
// staging.  Block mapping keeps the 4 j-blocks of one m-tile on one XCD.
// ---------------------------------------------------------------------------
__global__ __launch_bounds__(256) void gemm_kv(const unsigned short* __restrict__ X,
                                               const unsigned short* __restrict__ W,
                                               const float* __restrict__ bkv,
                                               unsigned short* __restrict__ Ko,
                                               unsigned short* __restrict__ Vo) {
    __shared__ __align__(16) unsigned short As[128 * 64];
    __shared__ __align__(16) unsigned short Bs[128 * 64];
    int t = threadIdx.x, wave = t >> 6, lane = t & 63;
    int wr = wave >> 1, wc = wave & 1;
    int bid = blockIdx.x;
    int m0 = (((bid >> 5) << 3) | (bid & 7)) * 128;   // same m-group -> same XCD slot
    int j0 = ((bid >> 3) & 3) * 128;

    f32x4 acc[4][4];
#pragma unroll
    for (int i = 0; i < 4; ++i)
#pragma unroll
        for (int j = 0; j < 4; ++j)
#pragma unroll
            for (int r = 0; r < 4; ++r) acc[i][j][r] = 0.f;

    for (int kb = 0; kb < 4; ++kb) {
        int k0 = kb * 64;
#pragma unroll
        for (int i = 0; i < 4; ++i) {
            int rbase = wave * 32 + i * 8;
            gld_lds16(X + (size_t)(m0 + rbase + (lane >> 3)) * 256 + k0 + (lane & 7) * 8,
                      &As[rbase * 64]);
            gld_lds16(W + (size_t)(j0 + rbase + (lane >> 3)) * 256 + k0 + (lane & 7) * 8,
                      &Bs[rbase * 64]);
        }
        __syncthreads();
#pragma unroll
        for (int kk = 0; kk < 64; kk += 32) {
            int koff = kk + (lane >> 4) * 8;
            int cl = koff >> 3;
            bf16x8 af[4], bf[4];
#pragma unroll
            for (int ti = 0; ti < 4; ++ti) {
                int r = wr * 64 + ti * 16 + (lane & 15);
                af[ti] = *(const bf16x8*)&As[r * 64 + ((cl ^ (r & 7)) << 3)];
            }
#pragma unroll
            for (int tj = 0; tj < 4; ++tj) {
                int c = wc * 64 + tj * 16 + (lane & 15);
                bf[tj] = *(const bf16x8*)&Bs[c * 64 + ((cl ^ (c & 7)) << 3)];
            }
#pragma unroll
            for (int ti = 0; ti < 4; ++ti)
#pragma unroll
                for (int tj = 0; tj < 4; ++tj)
                    acc[ti][tj] = __builtin_amdgcn_mfma_f32_16x16x32_bf16(
                        af[ti], bf[tj], acc[ti][tj], 0, 0, 0);
        }
        __syncthreads();
    }
    bool isK = (j0 < 256);
    unsigned short* base = isK ? Ko : Vo;
#pragma unroll
    for (int ti = 0; ti < 4; ++ti)
#pragma unroll
        for (int tj = 0; tj < 4; ++tj) {
            int col = j0 + wc * 64 + tj * 16 + (lane & 15);
            float bias = bkv[col];
            int outc = col & 255;
#pragma unroll
            for (int r = 0; r < 4; ++r) {
                int row = m0 + wr * 64 + ti * 16 + (lane >> 4) * 4 + r;
                base[(size_t)row * 256 + outc] = f2bf(acc[ti][tj][r] + bias);
            }
        }
}

// ---------------------------------------------------------------------------
// Fused attention: chunk = 256 n, grid (32,16).  Deterministic partials.
// ---------------------------------------------------------------------------
__global__ __launch_bounds__(256) void attn_fused(
    const unsigned short* __restrict__ qb, const unsigned short* __restrict__ K,
    const unsigned short* __restrict__ V,
    float* __restrict__ upd_p,               // [16][32*2048]
    float* __restrict__ sums_p) {            // [16][256]
    __shared__ __align__(16) unsigned short qs[8 * 256];
    __shared__ __align__(16) float atf[8 * 256];
    __shared__ __align__(16) float pr[4][8 * 256];
    __shared__ float ssum[8];
    int b = blockIdx.x, ch = blockIdx.y, t = threadIdx.x;
    int wave = t >> 6, lane = t & 63;

    *(uint4*)&qs[t * 8] = ((const uint4*)(qb + b * 2048))[t];
    if (t < 8) ssum[t] = 0.f;
    __syncthreads();

    int sg = t >> 7, np = t & 127;
    int nbase = ch * 256 + np * 2;
    const unsigned short* kr = K + ((size_t)b * 4096 + nbase) * 256;
    float acc[4][2];
#pragma unroll
    for (int i = 0; i < 4; ++i) { acc[i][0] = 0.f; acc[i][1] = 0.f; }
    for (int c = 0; c < 32; ++c) {
        float qf[4][8];
#pragma unroll
        for (int si = 0; si < 4; ++si)
            unpack8(*(const uint4*)&qs[(sg * 4 + si) * 256 + c * 8], qf[si]);
#pragma unroll
        for (int r = 0; r < 2; ++r) {
            float kf[8];
            unpack8(*(const uint4*)(kr + (size_t)r * 256 + c * 8), kf);
#pragma unroll
            for (int si = 0; si < 4; ++si)
                acc[si][r] += qf[si][0] * kf[0] + qf[si][1] * kf[1] +
                              qf[si][2] * kf[2] + qf[si][3] * kf[3] +
                              qf[si][4] * kf[4] + qf[si][5] * kf[5] +
                              qf[si][6] * kf[6] + qf[si][7] * kf[7];
        }
    }
#pragma unroll
    for (int si = 0; si < 4; ++si) {
        atf[(sg * 4 + si) * 256 + np * 2 + 0] = acc[si][0] * 0.0625f;
        atf[(sg * 4 + si) * 256 + np * 2 + 1] = acc[si][1] * 0.0625f;
    }
    __syncthreads();

    {
        int n = t;
        float v[8];
#pragma unroll
        for (int s = 0; s < 8; ++s) v[s] = atf[s * 256 + n];
        float m = v[0];
#pragma unroll
        for (int s = 1; s < 8; ++s) m = fmaxf(m, v[s]);
        float sum = 0.f;
#pragma unroll
        for (int s = 0; s < 8; ++s) { v[s] = __expf(v[s] - m); sum += v[s]; }
        float inv = 1.0f / sum;
        float ts[8];
#pragma unroll
        for (int s = 0; s < 8; ++s) {
            float a = v[s] * inv + 1e-8f;
            atf[s * 256 + n] = a;
            ts[s] = a;
        }
#pragma unroll
        for (int s = 0; s < 8; ++s) {
#pragma unroll
            for (int off = 32; off > 0; off >>= 1)
                ts[s] += __shfl_xor(ts[s], off, 64);
        }
        if (lane == 0) {
#pragma unroll
            for (int s = 0; s < 8; ++s) atomicAdd(&ssum[s], ts[s]);
        }
    }
    __syncthreads();
    if (t < 8) sums_p[ch * 256 + b * 8 + t] = ssum[t];

    float ua[8][4];
#pragma unroll
    for (int s = 0; s < 8; ++s)
#pragma unroll
        for (int k = 0; k < 4; ++k) ua[s][k] = 0.f;
    const unsigned short* vb = V + ((size_t)b * 4096 + ch * 256 + wave * 64) * 256 + lane * 4;
    for (int g = 0; g < 16; ++g) {
        int nl = wave * 64 + g * 4;
        float4 a4[8];
#pragma unroll
        for (int s = 0; s < 8; ++s) a4[s] = *(const float4*)&atf[s * 256 + nl];
        const unsigned short* vrow = vb + (size_t)g * 4 * 256;
#define UPD_STEP(kk, comp)                                                     \
        {                                                                      \
            uint2 vv = *(const uint2*)(vrow + (size_t)kk * 256);               \
            float v0 = bf2f_lo(vv.x), v1 = bf2f_hi(vv.x);                      \
            float v2 = bf2f_lo(vv.y), v3 = bf2f_hi(vv.y);                      \
            _Pragma("unroll")                                                  \
            for (int s = 0; s < 8; ++s) {                                      \
                float a = a4[s].comp;                                          \
                ua[s][0] += a * v0; ua[s][1] += a * v1;                        \
                ua[s][2] += a * v2; ua[s][3] += a * v3;                        \
            }                                                                  \
        }
        UPD_STEP(0, x) UPD_STEP(1, y) UPD_STEP(2, z) UPD_STEP(3, w)
#undef UPD_STEP
    }
#pragma unroll
    for (int s = 0; s < 8; ++s)
        *(float4*)&pr[wave][s * 256 + lane * 4] = *(float4*)ua[s];
    __syncthreads();
    for (int i = t; i < 2048; i += 256)
        upd_p[(size_t)ch * 65536 + (size_t)b * 2048 + i] =
            pr[0][i] + pr[1][i] + pr[2][i] + pr[3][i];
}

// ---------------------------------------------------------------------------
// Slot tail: reduce attn partials + gates GEMM + GRU + LN + MLP1 + MLP2 +
// residual (+ slot-LN + q GEMM unless last iter).  One block per batch.
// ---------------------------------------------------------------------------
__global__ __launch_bounds__(256) void slot_tail(
    const float* __restrict__ upd_p, const float* __restrict__ sums_p,
    const float* __restrict__ cur,
    const unsigned short* __restrict__ Wg, const float* __restrict__ bg,
    const float* __restrict__ g_mlp, const float* __restrict__ b_mlp,
    const unsigned short* __restrict__ W1b, const float* __restrict__ b1,
    const unsigned short* __restrict__ W2b, const float* __restrict__ b2,
    const float* __restrict__ g_slot, const float* __restrict__ b_slot,
    const unsigned short* __restrict__ Wqb, const float* __restrict__ bq,
    float* __restrict__ slots_out, unsigned short* __restrict__ qbuf,
    int do_q) {
    __shared__ float gts[8 * 1536];
    __shared__ float hn[2048];
    __shared__ float sn[2048];
    __shared__ __align__(16) unsigned short A1u[8 * 264];
    __shared__ __align__(16) unsigned short A1h[8 * 264];
    __shared__ __align__(16) unsigned short A1[8 * 264];
    __shared__ __align__(16) unsigned short A2[8 * 520];
    __shared__ float ssum8[8];
    int b = blockIdx.x, t = threadIdx.x;
    int wave = t >> 6, lane = t & 63;

    if (t < 8) {
        float s = 0.f;
#pragma unroll
        for (int c = 0; c < 16; ++c) s += sums_p[c * 256 + b * 8 + t];
        ssum8[t] = s;
    }
    __syncthreads();
    for (int idx = t; idx < 2048; idx += 256) {
        int row = idx >> 8, d = idx & 255;
        float us = 0.f;
#pragma unroll
        for (int c = 0; c < 16; ++c) us += upd_p[(size_t)c * 65536 + b * 2048 + idx];
        A1u[row * 264 + d] = f2bf(us / ssum8[row]);
        A1h[row * 264 + d] = f2bf(cur[(size_t)b * 2048 + idx]);
    }
    __syncthreads();

    {
        const unsigned short* Af = (wave < 2) ? A1u : A1h;
        bf16x8 af[8];
#pragma unroll
        for (int ks = 0; ks < 8; ++ks)
            af[ks] = *(const bf16x8*)&Af[(lane & 15) * 264 + ks * 32 + (lane >> 4) * 8];
#pragma unroll
        for (int nt = 0; nt < 24; ++nt) {
            int n0 = wave * 384 + nt * 16;
            f32x4 a = {0.f, 0.f, 0.f, 0.f};
#pragma unroll
            for (int ks = 0; ks < 8; ++ks) {
                bf16x8 bfr = *(const bf16x8*)(Wg + (size_t)(n0 + (lane & 15)) * 256 +
                                              ks * 32 + (lane >> 4) * 8);
                a = __builtin_amdgcn_mfma_f32_16x16x32_bf16(af[ks], bfr, a, 0, 0, 0);
            }
            int col = n0 + (lane & 15);
            float bs = bg[col];
#pragma unroll
            for (int r = 0; r < 4; ++r) {
                int row = (lane >> 4) * 4 + r;
                if (row < 8) gts[row * 1536 + col] = a[r] + bs;
            }
        }
    }
    __syncthreads();

#pragma unroll
    for (int p = 0; p < 8; ++p) {
        int idx = p * 256 + t;
        int s = idx >> 8, j = idx & 255;
        const float* gr = &gts[s * 1536];
        float r  = sigf(gr[j] + gr[768 + j]);
        float z  = sigf(gr[256 + j] + gr[1024 + j]);
        float nn = tanhf(gr[512 + j] + r * gr[1280 + j]);
        float h  = cur[(size_t)b * 2048 + idx];
        hn[idx] = (1.0f - z) * nn + z * h;
    }
    __syncthreads();

    {
        float4 g4 = *(const float4*)(g_mlp + lane * 4);
        float4 b4 = *(const float4*)(b_mlp + lane * 4);
#pragma unroll
        for (int rep = 0; rep < 2; ++rep) {
            int s = wave * 2 + rep;
            float4 x = *(const float4*)&hn[s * 256 + lane * 4];
            float sm = x.x + x.y + x.z + x.w;
            float sq = x.x * x.x + x.y * x.y + x.z * x.z + x.w * x.w;
#pragma unroll
            for (int off = 32; off > 0; off >>= 1) {
                sm += __shfl_xor(sm, off, 64);
                sq += __shfl_xor(sq, off, 64);
            }
            float mean = sm * (1.0f / 256.0f);
            float rstd = rsqrtf(sq * (1.0f / 256.0f) - mean * mean + 1e-3f);
            uint2 o;
            o.x = (uint32_t)f2bf((x.x - mean) * rstd * g4.x + b4.x) |
                  ((uint32_t)f2bf((x.y - mean) * rstd * g4.y + b4.y) << 16);
            o.y = (uint32_t)f2bf((x.z - mean) * rstd * g4.z + b4.z) |
                  ((uint32_t)f2bf((x.w - mean) * rstd * g4.w + b4.w) << 16);
            *(uint2*)&A1[s * 264 + lane * 4] = o;
        }
    }
    __syncthreads();

    {
        bf16x8 af[8];
#pragma unroll
        for (int ks = 0; ks < 8; ++ks)
            af[ks] = *(const bf16x8*)&A1[(lane & 15) * 264 + ks * 32 + (lane >> 4) * 8];
#pragma unroll
        for (int nt = 0; nt < 8; ++nt) {
            int n0 = (wave * 8 + nt) * 16;
            f32x4 a = {0.f, 0.f, 0.f, 0.f};
#pragma unroll
            for (int ks = 0; ks < 8; ++ks) {
                bf16x8 bfr = *(const bf16x8*)(W1b + (size_t)(n0 + (lane & 15)) * 256 +
                                              ks * 32 + (lane >> 4) * 8);
                a = __builtin_amdgcn_mfma_f32_16x16x32_bf16(af[ks], bfr, a, 0, 0, 0);
            }
            int col = n0 + (lane & 15);
            float bs = b1[col];
#pragma unroll
            for (int r = 0; r < 4; ++r) {
                int row = (lane >> 4) * 4 + r;
                if (row < 8) A2[row * 520 + col] = f2bf(fmaxf(a[r] + bs, 0.f));
            }
        }
    }
    __syncthreads();

    {
        bf16x8 af[16];
#pragma unroll
        for (int ks = 0; ks < 16; ++ks)
            af[ks] = *(const bf16x8*)&A2[(lane & 15) * 520 + ks * 32 + (lane >> 4) * 8];
#pragma unroll
        for (int nt = 0; nt < 4; ++nt) {
            int n0 = (wave * 4 + nt) * 16;
            f32x4 a = {0.f, 0.f, 0.f, 0.f};
#pragma unroll
            for (int ks = 0; ks < 16; ++ks) {
                bf16x8 bfr = *(const bf16x8*)(W2b + (size_t)(n0 + (lane & 15)) * 512 +
                                              ks * 32 + (lane >> 4) * 8);
                a = __builtin_amdgcn_mfma_f32_16x16x32_bf16(af[ks], bfr, a, 0, 0, 0);
            }
            int col = n0 + (lane & 15);
            float bs = b2[col];
#pragma unroll
            for (int r = 0; r < 4; ++r) {
                int row = (lane >> 4) * 4 + r;
                if (row < 8) {
                    float v = a[r] + bs + hn[row * 256 + col];
                    sn[row * 256 + col] = v;
                    slots_out[((size_t)b * 8 + row) * 256 + col] = v;
                }
            }
        }
    }
    if (!do_q) return;
    __syncthreads();

    {
        float4 g4 = *(const float4*)(g_slot + lane * 4);
        float4 b4 = *(const float4*)(b_slot + lane * 4);
#pragma unroll
        for (int rep = 0; rep < 2; ++rep) {
            int s = wave * 2 + rep;
            float4 x = *(const float4*)&sn[s * 256 + lane * 4];
            float sm = x.x + x.y + x.z + x.w;
            float sq = x.x * x.x + x.y * x.y + x.z * x.z + x.w * x.w;
#pragma unroll
            for (int off = 32; off > 0; off >>= 1) {
                sm += __shfl_xor(sm, off, 64);
                sq += __shfl_xor(sq, off, 64);
            }
            float mean = sm * (1.0f / 256.0f);
            float rstd = rsqrtf(sq * (1.0f / 256.0f) - mean * mean + 1e-3f);
            uint2 o;
            o.x = (uint32_t)f2bf((x.x - mean) * rstd * g4.x + b4.x) |
                  ((uint32_t)f2bf((x.y - mean) * rstd * g4.y + b4.y) << 16);
            o.y = (uint32_t)f2bf((x.z - mean) * rstd * g4.z + b4.z) |
                  ((uint32_t)f2bf((x.w - mean) * rstd * g4.w + b4.w) << 16);
            *(uint2*)&A1[s * 264 + lane * 4] = o;
        }
    }
    __syncthreads();

    {
        bf16x8 af[8];
#pragma unroll
        for (int ks = 0; ks < 8; ++ks)
            af[ks] = *(const bf16x8*)&A1[(lane & 15) * 264 + ks * 32 + (lane >> 4) * 8];
#pragma unroll
        for (int nt = 0; nt < 4; ++nt) {
            int n0 = (wave * 4 + nt) * 16;
            f32x4 a = {0.f, 0.f, 0.f, 0.f};
#pragma unroll
            for (int ks = 0; ks < 8; ++ks) {
                bf16x8 bfr = *(const bf16x8*)(Wqb + (size_t)(n0 + (lane & 15)) * 256 +
                                              ks * 32 + (lane >> 4) * 8);
                a = __builtin_amdgcn_mfma_f32_16x16x32_bf16(af[ks], bfr, a, 0, 0, 0);
            }
            int col = n0 + (lane & 15);
            float bs = bq[col];
#pragma unroll
            for (int r = 0; r < 4; ++r) {
                int row = (lane >> 4) * 4 + r;
                if (row < 8)
                    qbuf[((size_t)b * 8 + row) * 256 + col] = f2bf(a[r] + bs);
            }
        }
    }
}

// ---------------------------------------------------------------------------
extern "C" void kernel_launch(void* const* d_in, const int* in_sizes, int n_in,
                              void* d_out, int out_size, void* d_ws, size_t ws_size,
                              hipStream_t stream) {
    const float* inputs    = (const float*)d_in[0];
    const float* slots_in  = (const float*)d_in[1];
    const float* ln_in_g   = (const float*)d_in[3];
    const float* ln_in_b   = (const float*)d_in[4];
    const float* ln_slot_g = (const float*)d_in[5];
    const float* ln_slot_b = (const float*)d_in[6];
    const float* ln_mlp_g  = (const float*)d_in[7];
    const float* ln_mlp_b  = (const float*)d_in[8];
    const float* Wq   = (const float*)d_in[9];
    const float* bq   = (const float*)d_in[10];
    const float* Wk   = (const float*)d_in[11];
    const float* bk   = (const float*)d_in[12];
    const float* Wv   = (const float*)d_in[13];
    const float* bv   = (const float*)d_in[14];
    const float* W_ih = (const float*)d_in[15];
    const float* b_ih = (const float*)d_in[16];
    const float* W_hh = (const float*)d_in[17];
    const float* b_hh = (const float*)d_in[18];
    const float* W1   = (const float*)d_in[19];
    const float* b1   = (const float*)d_in[20];
    const float* W2   = (const float*)d_in[21];
    const float* b2   = (const float*)d_in[22];

    char* p = (char*)d_ws;
    size_t off = 0;
    auto take = [&](size_t bytes) -> char* {
        char* r = p + off;
        off += (bytes + 255) & ~(size_t)255;
        return r;
    };
    unsigned short* xbf  = (unsigned short*)take((size_t)131072 * 256 * 2);
    unsigned short* Kb   = (unsigned short*)take((size_t)131072 * 256 * 2);
    unsigned short* Vb   = (unsigned short*)take((size_t)131072 * 256 * 2);
    unsigned short* Wkv  = (unsigned short*)take(131072 * 2);
    unsigned short* Wg   = (unsigned short*)take(393216 * 2);
    unsigned short* W1b  = (unsigned short*)take(131072 * 2);
    unsigned short* W2b  = (unsigned short*)take(131072 * 2);
    unsigned short* Wqb  = (unsigned short*)take(65536 * 2);
    float* bkv   = (float*)take(512 * 4);
    float* bg    = (float*)take(1536 * 4);
    unsigned short* qbuf = (unsigned short*)take(65536 * 2);
    float* upd_p = (float*)take((size_t)16 * 65536 * 4);
    float* sums_p= (float*)take(16 * 256 * 4);
    float* sA    = (float*)take(65536 * 4);
    float* sB    = (float*)take(65536 * 4);

    // Wqb (bf16 Wq for slot_tail's q-GEMM) still needed -> fold into prep cvt
    // via a tiny extra segment? Simpler: cvt it inside prep's cvt range.
    // (Wqb conversion appended to cvt segment below via extra blocks.)

    prep_k<<<36128, 256, 0, stream>>>(inputs, ln_in_g, ln_in_b, xbf,
                                      Wk, Wv, W_ih, W_hh, W1, W2,
                                      bk, bv, b_ih, b_hh,
                                      Wkv, Wg, W1b, W2b, bkv, bg,
                                      slots_in, ln_slot_g, ln_slot_b, Wq, bq, qbuf);
    // Wqb cvt (small, 256 blocks) — independent of prep's consumers until
    // slot_tail, runs concurrently-ish right after.
    // Reuse prep's cvt slot: separate micro-kernel to keep prep simple.
    {
        struct L { static __global__ void k(const float* __restrict__ Wq,
                                            unsigned short* __restrict__ Wqb) {
            int i = blockIdx.x * 256 + threadIdx.x;
            Wqb[i] = f2bf(Wq[i]);
        } };
        L::k<<<256, 256, 0, stream>>>(Wq, Wqb);
    }
    gemm_kv<<<4096, 256, 0, stream>>>(xbf, Wkv, bkv, Kb, Vb);

    const float* cur = slots_in;
    float* nxt[3] = {sA, sB, (float*)d_out};
    for (int it = 0; it < 3; ++it) {
        attn_fused<<<dim3(32, 16), 256, 0, stream>>>(qbuf, Kb, Vb, upd_p, sums_p);
        slot_tail<<<32, 256, 0, stream>>>(upd_p, sums_p, cur, Wg, bg,
                                          ln_mlp_g, ln_mlp_b, W1b, b1, W2b, b2,
                                          ln_slot_g, ln_slot_b, Wqb, bq,
                                          nxt[it], qbuf, it < 2 ? 1 : 0);
        cur = nxt[it];
    }
    (void)in_sizes; (void)n_in; (void)out_size; (void)ws_size;
}

// Round 6
// 558.584 us; speedup vs baseline: 1.1901x; 1.1067x over previous
//
#include <hip/hip_runtime.h>
#include <stdint.h>

// B=32, N=4096, D=256, S=8, H_MLP=512, 3 iterations.

typedef __attribute__((ext_vector_type(8))) short bf16x8;
typedef __attribute__((ext_vector_type(4))) float f32x4;

__device__ __forceinline__ float bf2f_lo(uint32_t u) {
    union { uint32_t u; float f; } v; v.u = u << 16; return v.f;
}
__device__ __forceinline__ float bf2f_hi(uint32_t u) {
    union { uint32_t u; float f; } v; v.u = u & 0xffff0000u; return v.f;
}
__device__ __forceinline__ unsigned short f2bf(float f) {
    union { float f; uint32_t u; } v; v.f = f;
    return (unsigned short)((v.u + 0x7fffu + ((v.u >> 16) & 1u)) >> 16);
}
__device__ __forceinline__ void unpack8(uint4 v, float* f) {
    f[0] = bf2f_lo(v.x); f[1] = bf2f_hi(v.x); f[2] = bf2f_lo(v.y); f[3] = bf2f_hi(v.y);
    f[4] = bf2f_lo(v.z); f[5] = bf2f_hi(v.z); f[6] = bf2f_lo(v.w); f[7] = bf2f_hi(v.w);
}
__device__ __forceinline__ float sigf(float x) { return 1.0f / (1.0f + __expf(-x)); }
__device__ __forceinline__ void gld_lds16(const void* g, void* l) {
    __builtin_amdgcn_global_load_lds(
        (__attribute__((address_space(1))) unsigned int*)g,
        (__attribute__((address_space(3))) unsigned int*)l, 16, 0, 0);
}

// ---------------------------------------------------------------------------
// prep_k grid segments:
//   [0, 8192)       LN(inputs): 16 rows/block, 4 rows/wave (latency-hiding)
//   [8192, 11520)   weight cvt fp32->bf16 (Wkv swizzled)
//   [11520, 11552)  q0 = LN_slot(slots_in) @ Wq^T + bq
//   [11552, 11617)  zero upd/sums accumulators for iteration 0
// ---------------------------------------------------------------------------
__global__ __launch_bounds__(256) void prep_k(
    const float* __restrict__ in, const float* __restrict__ ln_in_g,
    const float* __restrict__ ln_in_b, unsigned short* __restrict__ xbf,
    const float* __restrict__ Wk, const float* __restrict__ Wv,
    const float* __restrict__ W_ih, const float* __restrict__ W_hh,
    const float* __restrict__ W1, const float* __restrict__ W2,
    const float* __restrict__ bk, const float* __restrict__ bv,
    const float* __restrict__ b_ih, const float* __restrict__ b_hh,
    unsigned short* __restrict__ Wkv, unsigned short* __restrict__ Wg,
    unsigned short* __restrict__ W1b, unsigned short* __restrict__ W2b,
    float* __restrict__ bkv, float* __restrict__ bg,
    const float* __restrict__ slots_in, const float* __restrict__ g_slot,
    const float* __restrict__ b_slot, const float* __restrict__ Wq,
    const float* __restrict__ bq, unsigned short* __restrict__ qbuf,
    float* __restrict__ upd) {
    __shared__ __align__(16) unsigned short A1[8 * 264];
    int bid = blockIdx.x, t = threadIdx.x;
    int wave = t >> 6, lane = t & 63;

    if (bid < 8192) {
        // ---- LayerNorm inputs: 4 rows per wave, loads all in flight ----
        size_t rb = (size_t)bid * 16 + wave * 4;
        const float* rp = in + rb * 256 + lane * 4;
        float4 x0 = *(const float4*)(rp);
        float4 x1 = *(const float4*)(rp + 256);
        float4 x2 = *(const float4*)(rp + 512);
        float4 x3 = *(const float4*)(rp + 768);
        float s0 = x0.x + x0.y + x0.z + x0.w, q0 = x0.x*x0.x + x0.y*x0.y + x0.z*x0.z + x0.w*x0.w;
        float s1 = x1.x + x1.y + x1.z + x1.w, q1 = x1.x*x1.x + x1.y*x1.y + x1.z*x1.z + x1.w*x1.w;
        float s2 = x2.x + x2.y + x2.z + x2.w, q2 = x2.x*x2.x + x2.y*x2.y + x2.z*x2.z + x2.w*x2.w;
        float s3 = x3.x + x3.y + x3.z + x3.w, q3 = x3.x*x3.x + x3.y*x3.y + x3.z*x3.z + x3.w*x3.w;
#pragma unroll
        for (int off = 32; off > 0; off >>= 1) {
            s0 += __shfl_xor(s0, off, 64);  q0 += __shfl_xor(q0, off, 64);
            s1 += __shfl_xor(s1, off, 64);  q1 += __shfl_xor(q1, off, 64);
            s2 += __shfl_xor(s2, off, 64);  q2 += __shfl_xor(q2, off, 64);
            s3 += __shfl_xor(s3, off, 64);  q3 += __shfl_xor(q3, off, 64);
        }
        float4 g4 = *(const float4*)(ln_in_g + lane * 4);
        float4 b4 = *(const float4*)(ln_in_b + lane * 4);
        float4 xs[4] = {x0, x1, x2, x3};
        float ss[4] = {s0, s1, s2, s3}, qq[4] = {q0, q1, q2, q3};
#pragma unroll
        for (int i = 0; i < 4; ++i) {
            float mean = ss[i] * (1.0f / 256.0f);
            float rstd = rsqrtf(qq[i] * (1.0f / 256.0f) - mean * mean + 1e-3f);
            float4 x = xs[i];
            uint2 o;
            o.x = (uint32_t)f2bf((x.x - mean) * rstd * g4.x + b4.x) |
                  ((uint32_t)f2bf((x.y - mean) * rstd * g4.y + b4.y) << 16);
            o.y = (uint32_t)f2bf((x.z - mean) * rstd * g4.z + b4.z) |
                  ((uint32_t)f2bf((x.w - mean) * rstd * g4.w + b4.w) << 16);
            size_t row = rb + i;
            int dst = (((lane >> 1) ^ ((int)row & 7)) << 3) + (lane & 1) * 4;
            *(uint2*)(xbf + row * 256 + dst) = o;
        }
        return;
    }
    if (bid < 11520) {
        int i = (bid - 8192) * 256 + t;
        if (i < 131072) {
            float v = (i < 65536) ? Wk[i] : Wv[i - 65536];
            int col = i >> 8, k = i & 255;
            int dk = ((((k >> 3) ^ (col & 7)) << 3) | (k & 7));
            Wkv[col * 256 + dk] = f2bf(v);
        } else if (i < 524288) {
            int j = i - 131072;
            Wg[j] = f2bf(j < 196608 ? W_ih[j] : W_hh[j - 196608]);
        } else if (i < 655360) W1b[i - 524288] = f2bf(W1[i - 524288]);
        else                   W2b[i - 655360] = f2bf(W2[i - 655360]);
        if (i < 512)           bkv[i] = (i < 256 ? bk[i] : bv[i - 256]);
        else if (i < 2048)   { int j = i - 512; bg[j] = (j < 768 ? b_ih[j] : b_hh[j - 768]); }
        return;
    }
    if (bid >= 11552) {
        // zero upd[65536] + sums[256] (contiguous)
        int i = (bid - 11552) * 1024 + t * 4;
        if (i < 65792) *(float4*)(upd + i) = make_float4(0.f, 0.f, 0.f, 0.f);
        return;
    }
    // ---- q0 segment: one block per batch ----
    int b = bid - 11520;
    {
        float4 g4 = *(const float4*)(g_slot + lane * 4);
        float4 b4 = *(const float4*)(b_slot + lane * 4);
#pragma unroll
        for (int rep = 0; rep < 2; ++rep) {
            int s = wave * 2 + rep;
            float4 x = *(const float4*)(slots_in + (size_t)b * 2048 + s * 256 + lane * 4);
            float sm = x.x + x.y + x.z + x.w;
            float sq = x.x * x.x + x.y * x.y + x.z * x.z + x.w * x.w;
#pragma unroll
            for (int off = 32; off > 0; off >>= 1) {
                sm += __shfl_xor(sm, off, 64);
                sq += __shfl_xor(sq, off, 64);
            }
            float mean = sm * (1.0f / 256.0f);
            float rstd = rsqrtf(sq * (1.0f / 256.0f) - mean * mean + 1e-3f);
            uint2 o;
            o.x = (uint32_t)f2bf((x.x - mean) * rstd * g4.x + b4.x) |
                  ((uint32_t)f2bf((x.y - mean) * rstd * g4.y + b4.y) << 16);
            o.y = (uint32_t)f2bf((x.z - mean) * rstd * g4.z + b4.z) |
                  ((uint32_t)f2bf((x.w - mean) * rstd * g4.w + b4.w) << 16);
            *(uint2*)&A1[s * 264 + lane * 4] = o;
        }
    }
    __syncthreads();
    {
        bf16x8 af[8];
#pragma unroll
        for (int ks = 0; ks < 8; ++ks)
            af[ks] = *(const bf16x8*)&A1[(lane & 15) * 264 + ks * 32 + (lane >> 4) * 8];
#pragma unroll
        for (int nt = 0; nt < 4; ++nt) {
            int n0 = (wave * 4 + nt) * 16;
            f32x4 a = {0.f, 0.f, 0.f, 0.f};
#pragma unroll
            for (int ks = 0; ks < 8; ++ks) {
                const float* wp = Wq + (size_t)(n0 + (lane & 15)) * 256 +
                                  ks * 32 + (lane >> 4) * 8;
                float4 wa = *(const float4*)wp;
                float4 wb = *(const float4*)(wp + 4);
                bf16x8 bfr;
                bfr[0] = (short)f2bf(wa.x); bfr[1] = (short)f2bf(wa.y);
                bfr[2] = (short)f2bf(wa.z); bfr[3] = (short)f2bf(wa.w);
                bfr[4] = (short)f2bf(wb.x); bfr[5] = (short)f2bf(wb.y);
                bfr[6] = (short)f2bf(wb.z); bfr[7] = (short)f2bf(wb.w);
                a = __builtin_amdgcn_mfma_f32_16x16x32_bf16(af[ks], bfr, a, 0, 0, 0);
            }
            int col = n0 + (lane & 15);
            float bs = bq[col];
#pragma unroll
            for (int r = 0; r < 4; ++r) {
                int row = (lane >> 4) * 4 + r;
                if (row < 8)
                    qbuf[((size_t)b * 8 + row) * 256 + col] = f2bf(a[r] + bs);
            }
        }
    }
}

// ---------------------------------------------------------------------------
// K/V GEMM: XCD swizzle + conflict-free swizzled LDS (unchanged from r5).
// ---------------------------------------------------------------------------
__global__ __launch_bounds__(256) void gemm_kv(const unsigned short* __restrict__ X,
                                               const unsigned short* __restrict__ W,
                                               const float* __restrict__ bkv,
                                               unsigned short* __restrict__ Ko,
                                               unsigned short* __restrict__ Vo) {
    __shared__ __align__(16) unsigned short As[128 * 64];
    __shared__ __align__(16) unsigned short Bs[128 * 64];
    int t = threadIdx.x, wave = t >> 6, lane = t & 63;
    int wr = wave >> 1, wc = wave & 1;
    int bid = blockIdx.x;
    int m0 = (((bid >> 5) << 3) | (bid & 7)) * 128;
    int j0 = ((bid >> 3) & 3) * 128;

    f32x4 acc[4][4];
#pragma unroll
    for (int i = 0; i < 4; ++i)
#pragma unroll
        for (int j = 0; j < 4; ++j)
#pragma unroll
            for (int r = 0; r < 4; ++r) acc[i][j][r] = 0.f;

    for (int kb = 0; kb < 4; ++kb) {
        int k0 = kb * 64;
#pragma unroll
        for (int i = 0; i < 4; ++i) {
            int rbase = wave * 32 + i * 8;
            gld_lds16(X + (size_t)(m0 + rbase + (lane >> 3)) * 256 + k0 + (lane & 7) * 8,
                      &As[rbase * 64]);
            gld_lds16(W + (size_t)(j0 + rbase + (lane >> 3)) * 256 + k0 + (lane & 7) * 8,
                      &Bs[rbase * 64]);
        }
        __syncthreads();
#pragma unroll
        for (int kk = 0; kk < 64; kk += 32) {
            int koff = kk + (lane >> 4) * 8;
            int cl = koff >> 3;
            bf16x8 af[4], bf[4];
#pragma unroll
            for (int ti = 0; ti < 4; ++ti) {
                int r = wr * 64 + ti * 16 + (lane & 15);
                af[ti] = *(const bf16x8*)&As[r * 64 + ((cl ^ (r & 7)) << 3)];
            }
#pragma unroll
            for (int tj = 0; tj < 4; ++tj) {
                int c = wc * 64 + tj * 16 + (lane & 15);
                bf[tj] = *(const bf16x8*)&Bs[c * 64 + ((cl ^ (c & 7)) << 3)];
            }
#pragma unroll
            for (int ti = 0; ti < 4; ++ti)
#pragma unroll
                for (int tj = 0; tj < 4; ++tj)
                    acc[ti][tj] = __builtin_amdgcn_mfma_f32_16x16x32_bf16(
                        af[ti], bf[tj], acc[ti][tj], 0, 0, 0);
        }
        __syncthreads();
    }
    bool isK = (j0 < 256);
    unsigned short* base = isK ? Ko : Vo;
#pragma unroll
    for (int ti = 0; ti < 4; ++ti)
#pragma unroll
        for (int tj = 0; tj < 4; ++tj) {
            int col = j0 + wc * 64 + tj * 16 + (lane & 15);
            float bias = bkv[col];
            int outc = col & 255;
#pragma unroll
            for (int r = 0; r < 4; ++r) {
                int row = m0 + wr * 64 + ti * 16 + (lane >> 4) * 4 + r;
                base[(size_t)row * 256 + outc] = f2bf(acc[ti][tj][r] + bias);
            }
        }
}

// ---------------------------------------------------------------------------
// Fused attention: chunk = 256 n, grid (32,16).  Atomic accumulation into
// upd[256][256]/sums[256] (zeroed by prep for iter0, by slot_tail after).
// ---------------------------------------------------------------------------
__global__ __launch_bounds__(256) void attn_fused(
    const unsigned short* __restrict__ qb, const unsigned short* __restrict__ K,
    const unsigned short* __restrict__ V,
    float* __restrict__ upd, float* __restrict__ sums) {
    __shared__ __align__(16) unsigned short qs[8 * 256];
    __shared__ __align__(16) float atf[8 * 256];
    __shared__ __align__(16) float pr[4][8 * 256];
    __shared__ float ssum[8];
    int b = blockIdx.x, ch = blockIdx.y, t = threadIdx.x;
    int wave = t >> 6, lane = t & 63;

    *(uint4*)&qs[t * 8] = ((const uint4*)(qb + b * 2048))[t];
    if (t < 8) ssum[t] = 0.f;
    __syncthreads();

    int sg = t >> 7, np = t & 127;
    int nbase = ch * 256 + np * 2;
    const unsigned short* kr = K + ((size_t)b * 4096 + nbase) * 256;
    float acc[4][2];
#pragma unroll
    for (int i = 0; i < 4; ++i) { acc[i][0] = 0.f; acc[i][1] = 0.f; }
    for (int c = 0; c < 32; ++c) {
        float qf[4][8];
#pragma unroll
        for (int si = 0; si < 4; ++si)
            unpack8(*(const uint4*)&qs[(sg * 4 + si) * 256 + c * 8], qf[si]);
#pragma unroll
        for (int r = 0; r < 2; ++r) {
            float kf[8];
            unpack8(*(const uint4*)(kr + (size_t)r * 256 + c * 8), kf);
#pragma unroll
            for (int si = 0; si < 4; ++si)
                acc[si][r] += qf[si][0] * kf[0] + qf[si][1] * kf[1] +
                              qf[si][2] * kf[2] + qf[si][3] * kf[3] +
                              qf[si][4] * kf[4] + qf[si][5] * kf[5] +
                              qf[si][6] * kf[6] + qf[si][7] * kf[7];
        }
    }
#pragma unroll
    for (int si = 0; si < 4; ++si) {
        atf[(sg * 4 + si) * 256 + np * 2 + 0] = acc[si][0] * 0.0625f;
        atf[(sg * 4 + si) * 256 + np * 2 + 1] = acc[si][1] * 0.0625f;
    }
    __syncthreads();

    {
        int n = t;
        float v[8];
#pragma unroll
        for (int s = 0; s < 8; ++s) v[s] = atf[s * 256 + n];
        float m = v[0];
#pragma unroll
        for (int s = 1; s < 8; ++s) m = fmaxf(m, v[s]);
        float sum = 0.f;
#pragma unroll
        for (int s = 0; s < 8; ++s) { v[s] = __expf(v[s] - m); sum += v[s]; }
        float inv = 1.0f / sum;
        float ts[8];
#pragma unroll
        for (int s = 0; s < 8; ++s) {
            float a = v[s] * inv + 1e-8f;
            atf[s * 256 + n] = a;
            ts[s] = a;
        }
#pragma unroll
        for (int s = 0; s < 8; ++s) {
#pragma unroll
            for (int off = 32; off > 0; off >>= 1)
                ts[s] += __shfl_xor(ts[s], off, 64);
        }
        if (lane == 0) {
#pragma unroll
            for (int s = 0; s < 8; ++s) atomicAdd(&ssum[s], ts[s]);
        }
    }
    __syncthreads();
    if (t < 8) atomicAdd(&sums[b * 8 + t], ssum[t]);

    float ua[8][4];
#pragma unroll
    for (int s = 0; s < 8; ++s)
#pragma unroll
        for (int k = 0; k < 4; ++k) ua[s][k] = 0.f;
    const unsigned short* vb = V + ((size_t)b * 4096 + ch * 256 + wave * 64) * 256 + lane * 4;
    for (int g = 0; g < 16; ++g) {
        int nl = wave * 64 + g * 4;
        float4 a4[8];
#pragma unroll
        for (int s = 0; s < 8; ++s) a4[s] = *(const float4*)&atf[s * 256 + nl];
        const unsigned short* vrow = vb + (size_t)g * 4 * 256;
#define UPD_STEP(kk, comp)                                                     \
        {                                                                      \
            uint2 vv = *(const uint2*)(vrow + (size_t)kk * 256);               \
            float v0 = bf2f_lo(vv.x), v1 = bf2f_hi(vv.x);                      \
            float v2 = bf2f_lo(vv.y), v3 = bf2f_hi(vv.y);                      \
            _Pragma("unroll")                                                  \
            for (int s = 0; s < 8; ++s) {                                      \
                float a = a4[s].comp;                                          \
                ua[s][0] += a * v0; ua[s][1] += a * v1;                        \
                ua[s][2] += a * v2; ua[s][3] += a * v3;                        \
            }                                                                  \
        }
        UPD_STEP(0, x) UPD_STEP(1, y) UPD_STEP(2, z) UPD_STEP(3, w)
#undef UPD_STEP
    }
#pragma unroll
    for (int s = 0; s < 8; ++s)
        *(float4*)&pr[wave][s * 256 + lane * 4] = *(float4*)ua[s];
    __syncthreads();
    for (int i = t; i < 2048; i += 256) {
        float vsum = pr[0][i] + pr[1][i] + pr[2][i] + pr[3][i];
        atomicAdd(&upd[(size_t)b * 2048 + i], vsum);
    }
}

// ---------------------------------------------------------------------------
// Slot tail: 512 threads (8 waves).  Reads accumulated upd/sums, zeroes them
// for the next iteration, then gates GEMM + GRU + LN + MLP1 + MLP2 + resid
// (+ slot-LN + q GEMM unless last iter).  One block per batch.
// ---------------------------------------------------------------------------
__global__ __launch_bounds__(512, 1) void slot_tail(
    const float* __restrict__ upd, const float* __restrict__ sums,
    float* __restrict__ upd_w, float* __restrict__ sums_w,
    const float* __restrict__ cur,
    const unsigned short* __restrict__ Wg, const float* __restrict__ bg,
    const float* __restrict__ g_mlp, const float* __restrict__ b_mlp,
    const unsigned short* __restrict__ W1b, const float* __restrict__ b1,
    const unsigned short* __restrict__ W2b, const float* __restrict__ b2,
    const float* __restrict__ g_slot, const float* __restrict__ b_slot,
    const unsigned short* __restrict__ Wqb, const float* __restrict__ bq,
    float* __restrict__ slots_out, unsigned short* __restrict__ qbuf,
    int do_q) {
    __shared__ float gts[8 * 1536];
    __shared__ float hn[2048];
    __shared__ float sn[2048];
    __shared__ __align__(16) unsigned short A1u[8 * 264];
    __shared__ __align__(16) unsigned short A1h[8 * 264];
    __shared__ __align__(16) unsigned short A1[8 * 264];
    __shared__ __align__(16) unsigned short A2[8 * 520];
    __shared__ float ssum8[8];
    int b = blockIdx.x, t = threadIdx.x;
    int wave = t >> 6, lane = t & 63;

    if (t < 8) ssum8[t] = sums[b * 8 + t];
    __syncthreads();
    for (int idx = t; idx < 2048; idx += 512) {
        int row = idx >> 8, d = idx & 255;
        A1u[row * 264 + d] = f2bf(upd[(size_t)b * 2048 + idx] / ssum8[row]);
        A1h[row * 264 + d] = f2bf(cur[(size_t)b * 2048 + idx]);
    }
    __syncthreads();
    // zero accumulators for the next attn launch (deterministic, per-b slice)
    for (int idx = t; idx < 2048; idx += 512) upd_w[(size_t)b * 2048 + idx] = 0.f;
    if (t < 8) sums_w[b * 8 + t] = 0.f;

    // ---- gates GEMM: 96 col-tiles, waves 0-3 -> u@W_ih, 4-7 -> h@W_hh ----
    {
        const unsigned short* Af = (wave < 4) ? A1u : A1h;
        bf16x8 af[8];
#pragma unroll
        for (int ks = 0; ks < 8; ++ks)
            af[ks] = *(const bf16x8*)&Af[(lane & 15) * 264 + ks * 32 + (lane >> 4) * 8];
#pragma unroll
        for (int nt = 0; nt < 12; ++nt) {
            int n0 = wave * 192 + nt * 16;
            f32x4 a = {0.f, 0.f, 0.f, 0.f};
#pragma unroll
            for (int ks = 0; ks < 8; ++ks) {
                bf16x8 bfr = *(const bf16x8*)(Wg + (size_t)(n0 + (lane & 15)) * 256 +
                                              ks * 32 + (lane >> 4) * 8);
                a = __builtin_amdgcn_mfma_f32_16x16x32_bf16(af[ks], bfr, a, 0, 0, 0);
            }
            int col = n0 + (lane & 15);
            float bs = bg[col];
#pragma unroll
            for (int r = 0; r < 4; ++r) {
                int row = (lane >> 4) * 4 + r;
                if (row < 8) gts[row * 1536 + col] = a[r] + bs;
            }
        }
    }
    __syncthreads();

    // ---- GRU combine ----
#pragma unroll
    for (int p = 0; p < 4; ++p) {
        int idx = p * 512 + t;
        int s = idx >> 8, j = idx & 255;
        const float* gr = &gts[s * 1536];
        float r  = sigf(gr[j] + gr[768 + j]);
        float z  = sigf(gr[256 + j] + gr[1024 + j]);
        float nn = tanhf(gr[512 + j] + r * gr[1280 + j]);
        float h  = cur[(size_t)b * 2048 + idx];
        hn[idx] = (1.0f - z) * nn + z * h;
    }
    __syncthreads();

    // ---- LN(mlp) -> A1, one row per wave ----
    {
        float4 g4 = *(const float4*)(g_mlp + lane * 4);
        float4 b4 = *(const float4*)(b_mlp + lane * 4);
        int s = wave;
        float4 x = *(const float4*)&hn[s * 256 + lane * 4];
        float sm = x.x + x.y + x.z + x.w;
        float sq = x.x * x.x + x.y * x.y + x.z * x.z + x.w * x.w;
#pragma unroll
        for (int off = 32; off > 0; off >>= 1) {
            sm += __shfl_xor(sm, off, 64);
            sq += __shfl_xor(sq, off, 64);
        }
        float mean = sm * (1.0f / 256.0f);
        float rstd = rsqrtf(sq * (1.0f / 256.0f) - mean * mean + 1e-3f);
        uint2 o;
        o.x = (uint32_t)f2bf((x.x - mean) * rstd * g4.x + b4.x) |
              ((uint32_t)f2bf((x.y - mean) * rstd * g4.y + b4.y) << 16);
        o.y = (uint32_t)f2bf((x.z - mean) * rstd * g4.z + b4.z) |
              ((uint32_t)f2bf((x.w - mean) * rstd * g4.w + b4.w) << 16);
        *(uint2*)&A1[s * 264 + lane * 4] = o;
    }
    __syncthreads();

    // ---- MLP1: A2 = relu(A1 @ W1^T + b1), 32 tiles / 8 waves ----
    {
        bf16x8 af[8];
#pragma unroll
        for (int ks = 0; ks < 8; ++ks)
            af[ks] = *(const bf16x8*)&A1[(lane & 15) * 264 + ks * 32 + (lane >> 4) * 8];
#pragma unroll
        for (int nt = 0; nt < 4; ++nt) {
            int n0 = (wave * 4 + nt) * 16;
            f32x4 a = {0.f, 0.f, 0.f, 0.f};
#pragma unroll
            for (int ks = 0; ks < 8; ++ks) {
                bf16x8 bfr = *(const bf16x8*)(W1b + (size_t)(n0 + (lane & 15)) * 256 +
                                              ks * 32 + (lane >> 4) * 8);
                a = __builtin_amdgcn_mfma_f32_16x16x32_bf16(af[ks], bfr, a, 0, 0, 0);
            }
            int col = n0 + (lane & 15);
            float bs = b1[col];
#pragma unroll
            for (int r = 0; r < 4; ++r) {
                int row = (lane >> 4) * 4 + r;
                if (row < 8) A2[row * 520 + col] = f2bf(fmaxf(a[r] + bs, 0.f));
            }
        }
    }
    __syncthreads();

    // ---- MLP2: sn = A2 @ W2^T + b2 + hn, 16 tiles / 8 waves ----
    {
        bf16x8 af[16];
#pragma unroll
        for (int ks = 0; ks < 16; ++ks)
            af[ks] = *(const bf16x8*)&A2[(lane & 15) * 520 + ks * 32 + (lane >> 4) * 8];
#pragma unroll
        for (int nt = 0; nt < 2; ++nt) {
            int n0 = (wave * 2 + nt) * 16;
            f32x4 a = {0.f, 0.f, 0.f, 0.f};
#pragma unroll
            for (int ks = 0; ks < 16; ++ks) {
                bf16x8 bfr = *(const bf16x8*)(W2b + (size_t)(n0 + (lane & 15)) * 512 +
                                              ks * 32 + (lane >> 4) * 8);
                a = __builtin_amdgcn_mfma_f32_16x16x32_bf16(af[ks], bfr, a, 0, 0, 0);
            }
            int col = n0 + (lane & 15);
            float bs = b2[col];
#pragma unroll
            for (int r = 0; r < 4; ++r) {
                int row = (lane >> 4) * 4 + r;
                if (row < 8) {
                    float v = a[r] + bs + hn[row * 256 + col];
                    sn[row * 256 + col] = v;
                    slots_out[((size_t)b * 8 + row) * 256 + col] = v;
                }
            }
        }
    }
    if (!do_q) return;
    __syncthreads();

    // ---- LN(slot) on sn -> A1 ----
    {
        float4 g4 = *(const float4*)(g_slot + lane * 4);
        float4 b4 = *(const float4*)(b_slot + lane * 4);
        int s = wave;
        float4 x = *(const float4*)&sn[s * 256 + lane * 4];
        float sm = x.x + x.y + x.z + x.w;
        float sq = x.x * x.x + x.y * x.y + x.z * x.z + x.w * x.w;
#pragma unroll
        for (int off = 32; off > 0; off >>= 1) {
            sm += __shfl_xor(sm, off, 64);
            sq += __shfl_xor(sq, off, 64);
        }
        float mean = sm * (1.0f / 256.0f);
        float rstd = rsqrtf(sq * (1.0f / 256.0f) - mean * mean + 1e-3f);
        uint2 o;
        o.x = (uint32_t)f2bf((x.x - mean) * rstd * g4.x + b4.x) |
              ((uint32_t)f2bf((x.y - mean) * rstd * g4.y + b4.y) << 16);
        o.y = (uint32_t)f2bf((x.z - mean) * rstd * g4.z + b4.z) |
              ((uint32_t)f2bf((x.w - mean) * rstd * g4.w + b4.w) << 16);
        *(uint2*)&A1[s * 264 + lane * 4] = o;
    }
    __syncthreads();

    // ---- q = A1 @ Wq^T + bq, 16 tiles / 8 waves ----
    {
        bf16x8 af[8];
#pragma unroll
        for (int ks = 0; ks < 8; ++ks)
            af[ks] = *(const bf16x8*)&A1[(lane & 15) * 264 + ks * 32 + (lane >> 4) * 8];
#pragma unroll
        for (int nt = 0; nt < 2; ++nt) {
            int n0 = (wave * 2 + nt) * 16;
            f32x4 a = {0.f, 0.f, 0.f, 0.f};
#pragma unroll
            for (int ks = 0; ks < 8; ++ks) {
                bf16x8 bfr = *(const bf16x8*)(Wqb + (size_t)(n0 + (lane & 15)) * 256 +
                                              ks * 32 + (lane >> 4) * 8);
                a = __builtin_amdgcn_mfma_f32_16x16x32_bf16(af[ks], bfr, a, 0, 0, 0);
            }
            int col = n0 + (lane & 15);
            float bs = bq[col];
#pragma unroll
            for (int r = 0; r < 4; ++r) {
                int row = (lane >> 4) * 4 + r;
                if (row < 8)
                    qbuf[((size_t)b * 8 + row) * 256 + col] = f2bf(a[r] + bs);
            }
        }
    }
}

// ---------------------------------------------------------------------------
extern "C" void kernel_launch(void* const* d_in, const int* in_sizes, int n_in,
                              void* d_out, int out_size, void* d_ws, size_t ws_size,
                              hipStream_t stream) {
    const float* inputs    = (const float*)d_in[0];
    const float* slots_in  = (const float*)d_in[1];
    const float* ln_in_g   = (const float*)d_in[3];
    const float* ln_in_b   = (const float*)d_in[4];
    const float* ln_slot_g = (const float*)d_in[5];
    const float* ln_slot_b = (const float*)d_in[6];
    const float* ln_mlp_g  = (const float*)d_in[7];
    const float* ln_mlp_b  = (const float*)d_in[8];
    const float* Wq   = (const float*)d_in[9];
    const float* bq   = (const float*)d_in[10];
    const float* Wk   = (const float*)d_in[11];
    const float* bk   = (const float*)d_in[12];
    const float* Wv   = (const float*)d_in[13];
    const float* bv   = (const float*)d_in[14];
    const float* W_ih = (const float*)d_in[15];
    const float* b_ih = (const float*)d_in[16];
    const float* W_hh = (const float*)d_in[17];
    const float* b_hh = (const float*)d_in[18];
    const float* W1   = (const float*)d_in[19];
    const float* b1   = (const float*)d_in[20];
    const float* W2   = (const float*)d_in[21];
    const float* b2   = (const float*)d_in[22];

    char* p = (char*)d_ws;
    size_t off = 0;
    auto take = [&](size_t bytes) -> char* {
        char* r = p + off;
        off += (bytes + 255) & ~(size_t)255;
        return r;
    };
    unsigned short* xbf  = (unsigned short*)take((size_t)131072 * 256 * 2);
    unsigned short* Kb   = (unsigned short*)take((size_t)131072 * 256 * 2);
    unsigned short* Vb   = (unsigned short*)take((size_t)131072 * 256 * 2);
    unsigned short* Wkv  = (unsigned short*)take(131072 * 2);
    unsigned short* Wg   = (unsigned short*)take(393216 * 2);
    unsigned short* W1b  = (unsigned short*)take(131072 * 2);
    unsigned short* W2b  = (unsigned short*)take(131072 * 2);
    unsigned short* Wqb  = (unsigned short*)take(65536 * 2);
    float* bkv   = (float*)take(512 * 4);
    float* bg    = (float*)take(1536 * 4);
    unsigned short* qbuf = (unsigned short*)take(65536 * 2);
    float* upd   = (float*)take((65536 + 256) * 4);   // upd + sums contiguous
    float* sums  = upd + 65536;
    float* sA    = (float*)take(65536 * 4);
    float* sB    = (float*)take(65536 * 4);

    prep_k<<<11617, 256, 0, stream>>>(inputs, ln_in_g, ln_in_b, xbf,
                                      Wk, Wv, W_ih, W_hh, W1, W2,
                                      bk, bv, b_ih, b_hh,
                                      Wkv, Wg, W1b, W2b, bkv, bg,
                                      slots_in, ln_slot_g, ln_slot_b, Wq, bq, qbuf,
                                      upd);
    {
        struct L { static __global__ void k(const float* __restrict__ Wq,
                                            unsigned short* __restrict__ Wqb) {
            int i = blockIdx.x * 256 + threadIdx.x;
            Wqb[i] = f2bf(Wq[i]);
        } };
        L::k<<<256, 256, 0, stream>>>(Wq, Wqb);
    }
    gemm_kv<<<4096, 256, 0, stream>>>(xbf, Wkv, bkv, Kb, Vb);

    const float* cur = slots_in;
    float* nxt[3] = {sA, sB, (float*)d_out};
    for (int it = 0; it < 3; ++it) {
        attn_fused<<<dim3(32, 16), 256, 0, stream>>>(qbuf, Kb, Vb, upd, sums);
        slot_tail<<<32, 512, 0, stream>>>(upd, sums, upd, sums, cur, Wg, bg,
                                          ln_mlp_g, ln_mlp_b, W1b, b1, W2b, b2,
                                          ln_slot_g, ln_slot_b, Wqb, bq,
                                          nxt[it], qbuf, it < 2 ? 1 : 0);
        cur = nxt[it];
    }
    (void)in_sizes; (void)n_in; (void)out_size; (void)ws_size;
}